// Round 4
// baseline (47.275 us; speedup 1.0000x reference)
//
#include <hip/hip_runtime.h>

#define B_ROWS 4194304
#define NTHREADS 256
#define NBLOCKS 2048
#define TASKS_PER_THREAD 2
// total tasks = B_ROWS/4 = 1048576 = NBLOCKS * NTHREADS * TASKS_PER_THREAD
#define TASK_STRIDE (NBLOCKS * NTHREADS)   // 524288

// Single fused kernel: per-thread 2 tasks (8 rows), wave+block reduce,
// one HW fp32 atomicAdd per block into d_out[0] (pre-zeroed by the
// graph-captured memset in kernel_launch).
__global__ __launch_bounds__(NTHREADS) void loss_fused_kernel(
    const float* __restrict__ outp,
    const float* __restrict__ tgt,
    const float* __restrict__ dist,
    float* __restrict__ out)
{
    float dd[5];
    #pragma unroll
    for (int c = 0; c < 5; ++c) dd[c] = dist[c];

    const float4* tp4 = (const float4*)tgt;
    const float4* op4 = (const float4*)outp;

    const int tid0 = blockIdx.x * NTHREADS + threadIdx.x;

    float acc = 0.0f;

    #pragma unroll
    for (int k = 0; k < TASKS_PER_THREAD; ++k) {
        const int task = tid0 + k * TASK_STRIDE;
        const int base = task * 5;           // 5 float4 = 20 floats = 4 rows

        float4 t0 = tp4[base + 0], t1 = tp4[base + 1], t2 = tp4[base + 2],
               t3 = tp4[base + 3], t4 = tp4[base + 4];
        float4 o0 = op4[base + 0], o1 = op4[base + 1], o2 = op4[base + 2],
               o3 = op4[base + 3], o4 = op4[base + 4];

        float tr[4][5] = {
            {t0.x, t0.y, t0.z, t0.w, t1.x},
            {t1.y, t1.z, t1.w, t2.x, t2.y},
            {t2.z, t2.w, t3.x, t3.y, t3.z},
            {t3.w, t4.x, t4.y, t4.z, t4.w}};
        float orr[4][5] = {
            {o0.x, o0.y, o0.z, o0.w, o1.x},
            {o1.y, o1.z, o1.w, o2.x, o2.y},
            {o2.z, o2.w, o3.x, o3.y, o3.z},
            {o3.w, o4.x, o4.y, o4.z, o4.w}};

        #pragma unroll
        for (int r = 0; r < 4; ++r) {
            // first-occurrence argmax (matches jnp.argmax) -> delta
            float m = tr[r][0];
            float delta = dd[0];
            #pragma unroll
            for (int c = 1; c < 5; ++c) {
                if (tr[r][c] > m) { m = tr[r][c]; delta = dd[c]; }
            }
            #pragma unroll
            for (int c = 0; c < 5; ++c) {
                acc += (orr[r][c] - tr[r][c]) * (fabsf(dd[c] - delta) + 1.0f);
            }
        }
    }

    // Wave (64-lane) shuffle reduce.
    #pragma unroll
    for (int off = 32; off > 0; off >>= 1) acc += __shfl_down(acc, off, 64);

    __shared__ float smem[NTHREADS / 64];
    const int lane = threadIdx.x & 63;
    const int wid  = threadIdx.x >> 6;
    if (lane == 0) smem[wid] = acc;
    __syncthreads();
    if (threadIdx.x == 0) {
        float s = 0.0f;
        #pragma unroll
        for (int w = 0; w < NTHREADS / 64; ++w) s += smem[w];
        // HW global_atomic_add_f32 (no CAS loop); scale so the atomic
        // accumulates the final mean directly.
        unsafeAtomicAdd(out, s * (1.0f / (float)B_ROWS));
    }
}

extern "C" void kernel_launch(void* const* d_in, const int* in_sizes, int n_in,
                              void* d_out, int out_size, void* d_ws, size_t ws_size,
                              hipStream_t stream)
{
    const float* outp = (const float*)d_in[0];   // output [B,5] f32
    const float* tgt  = (const float*)d_in[1];   // target [B,5] f32
    const float* dist = (const float*)d_in[2];   // distance [5] f32
    float* out = (float*)d_out;                  // scalar f32

    // Re-zero the accumulator every call (graph-captured async memset;
    // harness poisons d_out only once before timing).
    hipMemsetAsync(out, 0, sizeof(float), stream);
    loss_fused_kernel<<<NBLOCKS, NTHREADS, 0, stream>>>(outp, tgt, dist, out);
}

// Round 5
// 31.129 us; speedup vs baseline: 1.5187x; 1.5187x over previous
//
#include <hip/hip_runtime.h>

#define B_ROWS 4194304
#define NTHREADS 256
#define NBLOCKS 4096     // ntasks = B_ROWS/4 = 1048576 = NBLOCKS*NTHREADS, 1 task/thread

// Stage 1: each thread = one task (4 rows = 5 float4 per tensor), all 10
// global loads issued back-to-back, wave+block reduce, one store per block.
__global__ __launch_bounds__(NTHREADS) void loss_partial_kernel(
    const float* __restrict__ outp,
    const float* __restrict__ tgt,
    const float* __restrict__ dist,
    float* __restrict__ partials)
{
    float dd[5];
    #pragma unroll
    for (int c = 0; c < 5; ++c) dd[c] = dist[c];

    const float4* tp4 = (const float4*)tgt;
    const float4* op4 = (const float4*)outp;

    const int task = blockIdx.x * NTHREADS + threadIdx.x;
    const int base = task * 5;               // 5 float4 = 20 floats = 4 rows

    // Issue all 10 loads before any use.
    float4 t0 = tp4[base + 0], t1 = tp4[base + 1], t2 = tp4[base + 2],
           t3 = tp4[base + 3], t4 = tp4[base + 4];
    float4 o0 = op4[base + 0], o1 = op4[base + 1], o2 = op4[base + 2],
           o3 = op4[base + 3], o4 = op4[base + 4];

    float tr[4][5] = {
        {t0.x, t0.y, t0.z, t0.w, t1.x},
        {t1.y, t1.z, t1.w, t2.x, t2.y},
        {t2.z, t2.w, t3.x, t3.y, t3.z},
        {t3.w, t4.x, t4.y, t4.z, t4.w}};
    float orr[4][5] = {
        {o0.x, o0.y, o0.z, o0.w, o1.x},
        {o1.y, o1.z, o1.w, o2.x, o2.y},
        {o2.z, o2.w, o3.x, o3.y, o3.z},
        {o3.w, o4.x, o4.y, o4.z, o4.w}};

    float acc = 0.0f;
    #pragma unroll
    for (int r = 0; r < 4; ++r) {
        // first-occurrence argmax (matches jnp.argmax) -> delta
        float m = tr[r][0];
        float delta = dd[0];
        #pragma unroll
        for (int c = 1; c < 5; ++c) {
            if (tr[r][c] > m) { m = tr[r][c]; delta = dd[c]; }
        }
        #pragma unroll
        for (int c = 0; c < 5; ++c) {
            acc += (orr[r][c] - tr[r][c]) * (fabsf(dd[c] - delta) + 1.0f);
        }
    }

    // Wave (64-lane) shuffle reduce.
    #pragma unroll
    for (int off = 32; off > 0; off >>= 1) acc += __shfl_down(acc, off, 64);

    __shared__ float smem[NTHREADS / 64];
    const int lane = threadIdx.x & 63;
    const int wid  = threadIdx.x >> 6;
    if (lane == 0) smem[wid] = acc;
    __syncthreads();
    if (threadIdx.x == 0) {
        float s = 0.0f;
        #pragma unroll
        for (int w = 0; w < NTHREADS / 64; ++w) s += smem[w];
        partials[blockIdx.x] = s;    // distinct addresses: no atomic burst
    }
}

// Stage 2: reduce NBLOCKS partials, divide by B. One block, 1024 threads.
#define FTHREADS 1024
__global__ __launch_bounds__(FTHREADS) void loss_final_kernel(
    const float* __restrict__ partials,
    float* __restrict__ out)
{
    float acc = 0.0f;
    #pragma unroll
    for (int k = 0; k < NBLOCKS / FTHREADS; ++k)
        acc += partials[k * FTHREADS + threadIdx.x];

    #pragma unroll
    for (int off = 32; off > 0; off >>= 1) acc += __shfl_down(acc, off, 64);

    __shared__ float smem[FTHREADS / 64];
    const int lane = threadIdx.x & 63;
    const int wid  = threadIdx.x >> 6;
    if (lane == 0) smem[wid] = acc;
    __syncthreads();
    if (threadIdx.x == 0) {
        float s = 0.0f;
        #pragma unroll
        for (int w = 0; w < FTHREADS / 64; ++w) s += smem[w];
        out[0] = s / (float)B_ROWS;
    }
}

extern "C" void kernel_launch(void* const* d_in, const int* in_sizes, int n_in,
                              void* d_out, int out_size, void* d_ws, size_t ws_size,
                              hipStream_t stream)
{
    const float* outp = (const float*)d_in[0];   // output [B,5] f32
    const float* tgt  = (const float*)d_in[1];   // target [B,5] f32
    const float* dist = (const float*)d_in[2];   // distance [5] f32
    float* out = (float*)d_out;                  // scalar f32
    float* partials = (float*)d_ws;              // NBLOCKS floats of scratch

    loss_partial_kernel<<<NBLOCKS, NTHREADS, 0, stream>>>(outp, tgt, dist, partials);
    loss_final_kernel<<<1, FTHREADS, 0, stream>>>(partials, out);
}